// Round 4
// baseline (247.064 us; speedup 1.0000x reference)
//
#include <hip/hip_runtime.h>

// PhotometricLoss: fused warp + SSIM(3x3 avgpool, zero-pad) + L1 + masked mean.
// B=8, C=3, H=720, W=1280 fp32.
//
// R4: depth-2 software pipeline. Per step j (wave streams down rows):
//   phase 1: issue 6 right-gather loads for row rI (disp arrived last step)
//            + issue disp/left loads for row rI+1
//   phase 2: emit SSIM+L1 for center row rI-3 (pure VALU, ring regs only)
//   phase 3: consume gathers of row rI-1 (issued LAST step -> full step of
//            latency already elapsed), shuffles, write ring slot
// Every load has >= 1 full step (~500 VALU cyc) + inter-wave overlap to land.
// All edge handling via clamped addresses + 0/1 mask multiplies (branchless).

#define P_ALPHA 0.85f
#define P_C1 1e-4f
#define P_C2 9e-4f

constexpr int COLS  = 62;   // useful output columns per wave strip
constexpr int RPW   = 12;   // output rows per wave (720 = 15*4*12)
constexpr int WAVES = 4;    // waves per block

__global__ __launch_bounds__(256)
void photo_loss_kernel(const float* __restrict__ disp,
                       const float* __restrict__ left,
                       const float* __restrict__ right,
                       float* __restrict__ acc,   // acc[0]=sum(photo*valid), acc[1]=sum(valid)
                       int H, int W)
{
    __shared__ float redpv[WAVES];
    __shared__ float redv[WAVES];

    const int tid  = threadIdx.x;
    const int lane = tid & 63;
    const int w    = tid >> 6;
    const int b    = blockIdx.z;
    const int col  = blockIdx.x * COLS + lane - 1;          // -1 .. W (+halo)
    const int rowStart = (blockIdx.y * WAVES + w) * RPW;

    const int planeHW = H * W;
    const float* __restrict__ dispb = disp  + b * planeHW;
    const float* __restrict__ L0 = left  + (b * 3 + 0) * planeHW;
    const float* __restrict__ L1 = left  + (b * 3 + 1) * planeHW;
    const float* __restrict__ L2 = left  + (b * 3 + 2) * planeHW;
    const float* __restrict__ R0 = right + (b * 3 + 0) * planeHW;
    const float* __restrict__ R1 = right + (b * 3 + 1) * planeHW;
    const float* __restrict__ R2 = right + (b * 3 + 2) * planeHW;

    const float wm1f = (float)(W - 1);
    const int   colC = min(max(col, 0), W - 1);             // clamped address col
    const float colv = (col >= 0 && col < W) ? 1.f : 0.f;   // column validity
    const float ocm  = (lane >= 1 && lane <= COLS && col < W) ? 1.f : 0.f;  // output mask

    // 3-row register rings (all indices compile-time after full unroll)
    float rsx[3][3], rsy[3][3], rsxx[3][3], rsyy[3][3], rsxy[3][3];
    float l1r[3], vr[3];

    float sum_pv = 0.f, sum_v = 0.f;

    // emit center row held in ring slot cs (sums over all 3 slots, order-free)
    auto emit = [&](int cs) {
        const float inv9 = 1.f / 9.f;
        float ssim_sum = 0.f;
        #pragma unroll
        for (int c = 0; c < 3; ++c) {
            float mu_x = (rsx[c][0]  + rsx[c][1]  + rsx[c][2])  * inv9;
            float mu_y = (rsy[c][0]  + rsy[c][1]  + rsy[c][2])  * inv9;
            float exx  = (rsxx[c][0] + rsxx[c][1] + rsxx[c][2]) * inv9;
            float eyy  = (rsyy[c][0] + rsyy[c][1] + rsyy[c][2]) * inv9;
            float exy  = (rsxy[c][0] + rsxy[c][1] + rsxy[c][2]) * inv9;
            float sig_x  = fmaxf(exx - mu_x * mu_x, 0.f);
            float sig_y  = fmaxf(eyy - mu_y * mu_y, 0.f);
            float sig_xy = exy - mu_x * mu_y;
            float n  = (2.f * mu_x * mu_y + P_C1) * (2.f * sig_xy + P_C2);
            float dd = (mu_x * mu_x + mu_y * mu_y + P_C1) * (sig_x + sig_y + P_C2);
            float s  = (1.f - n * __builtin_amdgcn_rcpf(dd)) * 0.5f;  // dd >= C1*C2 > 0
            s = fminf(fmaxf(s, 0.f), 1.f);
            ssim_sum += s;
        }
        float photo = P_ALPHA * (ssim_sum * (1.f / 3.f))
                    + (1.f - P_ALPHA) * (l1r[cs] * (1.f / 3.f));
        sum_pv += photo * vr[cs] * ocm;
        sum_v  += vr[cs] * ocm;
    };

    // ---- pipeline state ----
    // dCur / xCur*: disp+left of the row whose gathers get ISSUED this step
    // g** / frP / mP / vP / xPrev*: gathers (in flight) + metadata of the row
    //                               to be CONSUMED this step
    float dCur, xCur0, xCur1, xCur2;
    {
        const int rc  = min(max(rowStart - 1, 0), H - 1);
        const int off = rc * W + colC;
        dCur = dispb[off]; xCur0 = L0[off]; xCur1 = L1[off]; xCur2 = L2[off];
    }
    float g00 = 0.f, g01 = 0.f, g10 = 0.f, g11 = 0.f, g20 = 0.f, g21 = 0.f;
    float frP = 0.f, mP = 0.f, vP = 0.f;
    float xPrev0 = 0.f, xPrev1 = 0.f, xPrev2 = 0.f;

    #pragma unroll
    for (int j = 0; j <= RPW + 3; ++j) {
        const int rI = rowStart - 1 + j;     // row whose gathers issue this step

        // ---- phase 1: issue gathers for row rI + disp/left for row rI+1 ----
        float ng00, ng01, ng10, ng11, ng20, ng21, frC, mC, vC;
        float dNext, xN0, xN1, xN2;
        if (j <= RPW + 1) {
            const int   rc = min(max(rI, 0), H - 1);
            const float rv = (rI >= 0 && rI < H) ? 1.f : 0.f;
            mC = rv * colv;

            const float xs  = (float)col - dCur;
            vC = (xs > 0.f && xs < wm1f) ? 1.f : 0.f;
            const float xcl = fminf(fmaxf(xs, 0.f), wm1f);
            const float xf  = floorf(xcl);
            frC = xcl - xf;
            const int i0 = (int)xf;
            const int i1 = min(i0 + 1, W - 1);
            const int ro = rc * W;
            ng00 = R0[ro + i0]; ng01 = R0[ro + i1];
            ng10 = R1[ro + i0]; ng11 = R1[ro + i1];
            ng20 = R2[ro + i0]; ng21 = R2[ro + i1];

            if (j <= RPW) {
                const int rn   = min(max(rI + 1, 0), H - 1);
                const int offn = rn * W + colC;
                dNext = dispb[offn];
                xN0 = L0[offn]; xN1 = L1[offn]; xN2 = L2[offn];
            }
        }

        // ---- phase 2: emit center row rowStart-4+j (ring slots intact) ----
        if (j >= 4) emit((j - 3) % 3);

        // ---- phase 3: consume gathers of row rI-1 (issued last step) ----
        if (j >= 1 && j <= RPW + 2) {
            const int s = (j - 1) % 3;       // compile-time after unroll
            const float omf = 1.f - frP;
            const float y0 = (omf * g00 + frP * g01) * mP;
            const float y1 = (omf * g10 + frP * g11) * mP;
            const float y2 = (omf * g20 + frP * g21) * mP;
            const float x0 = xPrev0 * mP;
            const float x1 = xPrev1 * mP;
            const float x2 = xPrev2 * mP;

            float xl, xr, yl, yr;
            xl = __shfl_up(x0, 1, 64); xr = __shfl_down(x0, 1, 64);
            yl = __shfl_up(y0, 1, 64); yr = __shfl_down(y0, 1, 64);
            rsx[0][s]  = xl + x0 + xr;
            rsy[0][s]  = yl + y0 + yr;
            rsxx[0][s] = xl * xl + x0 * x0 + xr * xr;
            rsyy[0][s] = yl * yl + y0 * y0 + yr * yr;
            rsxy[0][s] = xl * yl + x0 * y0 + xr * yr;

            xl = __shfl_up(x1, 1, 64); xr = __shfl_down(x1, 1, 64);
            yl = __shfl_up(y1, 1, 64); yr = __shfl_down(y1, 1, 64);
            rsx[1][s]  = xl + x1 + xr;
            rsy[1][s]  = yl + y1 + yr;
            rsxx[1][s] = xl * xl + x1 * x1 + xr * xr;
            rsyy[1][s] = yl * yl + y1 * y1 + yr * yr;
            rsxy[1][s] = xl * yl + x1 * y1 + xr * yr;

            xl = __shfl_up(x2, 1, 64); xr = __shfl_down(x2, 1, 64);
            yl = __shfl_up(y2, 1, 64); yr = __shfl_down(y2, 1, 64);
            rsx[2][s]  = xl + x2 + xr;
            rsy[2][s]  = yl + y2 + yr;
            rsxx[2][s] = xl * xl + x2 * x2 + xr * xr;
            rsyy[2][s] = yl * yl + y2 * y2 + yr * yr;
            rsxy[2][s] = xl * yl + x2 * y2 + xr * yr;

            l1r[s] = fabsf(x0 - y0) + fabsf(x1 - y1) + fabsf(x2 - y2);
            vr[s]  = vP;
        }

        // ---- rotate pipeline (dead pieces eliminated after unroll) ----
        if (j <= RPW + 1) {
            g00 = ng00; g01 = ng01; g10 = ng10; g11 = ng11; g20 = ng20; g21 = ng21;
            frP = frC; mP = mC; vP = vC;
            xPrev0 = xCur0; xPrev1 = xCur1; xPrev2 = xCur2;
        }
        if (j <= RPW) {
            dCur = dNext; xCur0 = xN0; xCur1 = xN1; xCur2 = xN2;
        }
    }

    // wave reduce (64 lanes) then cross-wave via tiny LDS
    #pragma unroll
    for (int off = 32; off > 0; off >>= 1) {
        sum_pv += __shfl_down(sum_pv, off, 64);
        sum_v  += __shfl_down(sum_v,  off, 64);
    }
    if (lane == 0) { redpv[w] = sum_pv; redv[w] = sum_v; }
    __syncthreads();
    if (tid == 0) {
        atomicAdd(&acc[0], redpv[0] + redpv[1] + redpv[2] + redpv[3]);
        atomicAdd(&acc[1], redv[0]  + redv[1]  + redv[2]  + redv[3]);
    }
}

__global__ void photo_loss_finalize(const float* __restrict__ acc,
                                    float* __restrict__ out)
{
    out[0] = acc[0] / fmaxf(acc[1], 1.f);
}

extern "C" void kernel_launch(void* const* d_in, const int* in_sizes, int n_in,
                              void* d_out, int out_size, void* d_ws, size_t ws_size,
                              hipStream_t stream)
{
    const float* disp  = (const float*)d_in[0];
    const float* left  = (const float*)d_in[1];
    const float* right = (const float*)d_in[2];
    float* out = (float*)d_out;
    float* acc = (float*)d_ws;

    const int B = 8, H = 720, W = 1280;

    hipMemsetAsync(acc, 0, 2 * sizeof(float), stream);

    // x: 21 strips of 62 cols; y: 720 / (4 waves * 12 rows) = 15; z: batch
    dim3 grid((W + COLS - 1) / COLS, H / (WAVES * RPW), B);
    dim3 block(256);
    photo_loss_kernel<<<grid, block, 0, stream>>>(disp, left, right, acc, H, W);
    photo_loss_finalize<<<1, 1, 0, stream>>>(acc, out);
}